// Round 5
// baseline (16910.825 us; speedup 1.0000x reference)
//
#include <hip/hip_runtime.h>
#include <math.h>

#define B 128
#define T 128
#define H 128
#define RH 4
#define M 64
#define W 128
#define VOCAB 512
#define IFACE 919
#define G4 512
#define DELTA 1e-6f
#define CLIPV 20.0f

#define MEMLD 132   // mem row stride (W=128 + 4) -> 528B rows, 16B aligned
#define LNKLD 67    // link row stride (M=64 + 3)

__device__ __forceinline__ float sigmoidf_(float x){ return 1.0f/(1.0f+expf(-x)); }
__device__ __forceinline__ float softplusf_(float x){
  return fmaxf(x, 0.0f) + log1pf(expf(-fabsf(x)));
}
__device__ __forceinline__ float waveAllSum(float v){
  for (int off=1; off<64; off<<=1) v += __shfl_xor(v, off, 64);
  return v;
}
__device__ __forceinline__ float waveAllMax(float v){
  for (int off=1; off<64; off<<=1) v = fmaxf(v, __shfl_xor(v, off, 64));
  return v;
}

__global__ void k_transpose(const float* __restrict__ in, float* __restrict__ out,
                            int rows, int cols, int use_cols){
  int idx = blockIdx.x*blockDim.x + threadIdx.x;
  int total = rows*use_cols;
  if (idx < total){
    int r = idx / use_cols, c = idx - r*use_cols;
    out[c*rows + r] = in[r*cols + c];
  }
}

// xw0[v][g] = emb[v]·w_ih0[g][0:128] + b_ih0[g] + b_hh0[g]  (coalesced via wih0T)
__global__ void k_xw0(const float* __restrict__ emb, const float* __restrict__ wih0T,
                      const float* __restrict__ b_ih0, const float* __restrict__ b_hh0,
                      float* __restrict__ xw0){
  __shared__ float e[H];
  int v = blockIdx.x, g = threadIdx.x;
  if (g < H) e[g] = emb[v*H + g];
  __syncthreads();
  float acc = b_ih0[g] + b_hh0[g];
  #pragma unroll 8
  for (int k=0;k<H;k++) acc += e[k]*wih0T[k*G4 + g];
  xw0[v*G4 + g] = acc;
}

// fused tail: per 32 (b,t) rows -> Y = stash·w_out^T + b_out -> logits -> out
__launch_bounds__(512, 1)
__global__ void k_tail(const float* __restrict__ stash, const float* __restrict__ w_out,
                       const float* __restrict__ b_out, const float* __restrict__ w_fc,
                       const float* __restrict__ b_fc, float* __restrict__ out){
  __shared__ __align__(16) float S[32*644];
  __shared__ float Y[32*129];
  const int tid = threadIdx.x;
  const long bt0 = (long)blockIdx.x*32;

  for (int idx = tid; idx < 32*640; idx += 512){
    int bt = idx / 640, k = idx - bt*640;
    S[bt*644 + k] = stash[(bt0+bt)*640 + k];
  }
  __syncthreads();
  { // Y[bt][o]
    int og = tid >> 5, bt = tid & 31;
    const float4* s4 = (const float4*)(S + bt*644);
    #pragma unroll
    for (int oo = 0; oo < 8; ++oo){
      int o = og*8 + oo;
      const float4* w4 = (const float4*)(w_out + (size_t)o*640);
      float acc = b_out[o];
      #pragma unroll 8
      for (int k4 = 0; k4 < 160; ++k4){
        float4 w = w4[k4], s = s4[k4];
        acc += w.x*s.x + w.y*s.y + w.z*s.z + w.w*s.w;
      }
      Y[bt*129 + o] = acc;
    }
  }
  __syncthreads();
  { // logits, coalesced on t
    int t = tid & 31, vg = tid >> 5;
    int b  = (int)(bt0 >> 7);
    int tb = (int)(bt0 & 127);
    const float* yr = Y + t*129;
    #pragma unroll 2
    for (int vv = 0; vv < 32; ++vv){
      int v = vg*32 + vv;
      const float4* w4 = (const float4*)(w_fc + (size_t)v*H);
      float acc = b_fc[v];
      #pragma unroll 8
      for (int k4 = 0; k4 < 32; ++k4){
        float4 w = w4[k4];
        int k = k4*4;
        acc += w.x*yr[k] + w.y*yr[k+1] + w.z*yr[k+2] + w.w*yr[k+3];
      }
      out[((size_t)b*VOCAB + v)*T + tb + t] = acc;
    }
  }
}

__launch_bounds__(512, 1)
__global__ void k_dnc(const int* __restrict__ tokens,
                      const float* __restrict__ xw0,
                      const float* __restrict__ whh0T,
                      const float* __restrict__ w1catT,
                      const float* __restrict__ b_ih1,
                      const float* __restrict__ b_hh1,
                      const float* __restrict__ wifaceT,
                      const float* __restrict__ b_iface,
                      const float* __restrict__ h0,
                      float* __restrict__ stash)
{
  const int b = blockIdx.x;
  const int tid = threadIdx.x;
  const int lane = tid & 63;
  const int wave = tid >> 6;

  __shared__ __align__(16) float hcat[2*H];           // h0 || h1
  __shared__ __align__(16) float c0s[H], c1s[H], outv[H];
  __shared__ __align__(16) float mem[M*MEMLD];
  __shared__ float link[M*LNKLD];
  __shared__ float prec[M], ww[M], usage[M];
  __shared__ float rw[RH*M];
  __shared__ __align__(16) float gates[G4];
  __shared__ __align__(16) float xi[920];
  __shared__ __align__(16) float rk[RH*W];
  __shared__ __align__(16) float wk[W];
  __shared__ float er[W], wv[W];
  __shared__ float memnorm[M];
  __shared__ float wcw[M], alloc_s[M];
  __shared__ float cwm[RH*M], fwd[RH*M], bwd[RH*M];
  __shared__ int   tok[T];
  __shared__ float rstr[RH], fg[RH], rmode[RH*3];
  __shared__ float s_wstr, s_ag, s_wg, s_wwsum, s_wkinv, s_rkinv[RH];

  // loop-invariant hoists
  const float b1sum = b_ih1[tid < G4 ? tid : 0] + b_hh1[tid < G4 ? tid : 0];
  const float bi0   = b_iface[tid];
  const float bi1   = (tid < IFACE-512) ? b_iface[tid+512] : 0.f;

  if (tid < H){
    float hv0 = h0[0*B*H + b*H + tid];
    float hv1 = h0[1*B*H + b*H + tid];
    hcat[tid]=hv0; hcat[H+tid]=hv1; c0s[tid]=hv0; c1s[tid]=hv1;
  }
  if (tid < T) tok[tid] = tokens[b*T + tid];
  for (int i = tid; i < M*MEMLD; i += 512) mem[i]=0.f;
  for (int i = tid; i < M*LNKLD; i += 512) link[i]=0.f;
  if (tid < M){ prec[tid]=0.f; ww[tid]=0.f; usage[tid]=0.f; }
  if (tid < RH*M) rw[tid]=0.f;
  __syncthreads();

  for (int t = 0; t < T; ++t){
    const long bt = (long)b*T + t;

    // ================= mv0: gates = xw0[token] + w_hh0^T · h0 =================
    {
      float xv = xw0[(size_t)tok[t]*G4 + tid];    // independent load, issued first
      const float* wp = whh0T + tid;
      float a0=0.f,a1=0.f,a2=0.f,a3=0.f;
      #pragma unroll
      for (int k=0;k<H;k+=4){
        a0 += hcat[k  ]*wp[(k  )*G4];
        a1 += hcat[k+1]*wp[(k+1)*G4];
        a2 += hcat[k+2]*wp[(k+2)*G4];
        a3 += hcat[k+3]*wp[(k+3)*G4];
      }
      gates[tid] = xv + ((a0+a1)+(a2+a3));
    }
    __syncthreads();
    // ---- pw0
    if (tid < H){
      float ig = sigmoidf_(gates[tid]);
      float ff = sigmoidf_(gates[H+tid]);
      float gg = tanhf(gates[2*H+tid]);
      float og = sigmoidf_(gates[3*H+tid]);
      float c2 = ff*c0s[tid] + ig*gg;
      c0s[tid] = c2;
      hcat[tid] = og*tanhf(c2);
    }
    __syncthreads();

    // ================= mv1: gates = b1 + w1cat^T · [h0,h1]  (K=256) ==========
    {
      const float* wp = w1catT + tid;
      float a0=0.f,a1=0.f,a2=0.f,a3=0.f;
      #pragma unroll 16
      for (int k=0;k<2*H;k+=4){
        a0 += hcat[k  ]*wp[(k  )*G4];
        a1 += hcat[k+1]*wp[(k+1)*G4];
        a2 += hcat[k+2]*wp[(k+2)*G4];
        a3 += hcat[k+3]*wp[(k+3)*G4];
      }
      gates[tid] = b1sum + ((a0+a1)+(a2+a3));
    }
    __syncthreads();
    // ---- pw1 (+ stash first 128)
    if (tid < H){
      float ig = sigmoidf_(gates[tid]);
      float ff = sigmoidf_(gates[H+tid]);
      float gg = tanhf(gates[2*H+tid]);
      float og = sigmoidf_(gates[3*H+tid]);
      float c2 = ff*c1s[tid] + ig*gg;
      c1s[tid] = c2;
      float h2 = og*tanhf(c2);
      hcat[H+tid] = h2;
      float ov = fminf(fmaxf(h2, -CLIPV), CLIPV);
      outv[tid] = ov;
      stash[bt*640 + tid] = ov;
    }
    __syncthreads();

    // ================= iface: xi = w_iface^T · outv + b ======================
    {
      const float* wp = wifaceT + tid;
      float a0=0.f,a1=0.f;
      float c0=0.f,c1=0.f;
      const float* wp2 = wifaceT + tid + 512;
      bool two = (tid < IFACE-512);
      #pragma unroll
      for (int k=0;k<H;k+=2){
        float h0v = outv[k], h1v = outv[k+1];
        a0 += h0v*wp[(k  )*IFACE];
        a1 += h1v*wp[(k+1)*IFACE];
        if (two){
          c0 += h0v*wp2[(k  )*IFACE];
          c1 += h1v*wp2[(k+1)*IFACE];
        }
      }
      xi[tid] = bi0 + a0 + a1;
      if (two) xi[tid+512] = bi1 + c0 + c1;
    }
    __syncthreads();

    // ================= parse interface =======================================
    rk[tid] = tanhf(xi[tid]);
    if (tid < W){
      wk[tid] = tanhf(xi[516+tid]);
      er[tid] = sigmoidf_(xi[645+tid]);
      wv[tid] = tanhf(xi[773+tid]);
    }
    if (tid < RH){
      rstr[tid] = softplusf_(xi[512+tid]);
      fg[tid]   = sigmoidf_(xi[901+tid]);
      float a0 = xi[907+3*tid], a1 = xi[908+3*tid], a2 = xi[909+3*tid];
      float mx = fmaxf(a0, fmaxf(a1,a2));
      float e0=expf(a0-mx), e1=expf(a1-mx), e2=expf(a2-mx);
      float s = e0+e1+e2;
      rmode[3*tid]=e0/s; rmode[3*tid+1]=e1/s; rmode[3*tid+2]=e2/s;
    }
    if (tid == 0){
      s_wstr = softplusf_(xi[644]);
      s_ag = sigmoidf_(xi[905]);
      s_wg = sigmoidf_(xi[906]);
    }
    __syncthreads();

    // ===== Phase ABC: pre-norms + RAW write-content dots (same mem scan),
    //       usage update, key norms — one barrier ============================
    {
      int row = tid >> 3, sub = tid & 7;
      const float4* mrow = (const float4*)(mem + row*MEMLD);
      const float4* wk4  = (const float4*)wk;
      float ss=0.f, d=0.f;
      #pragma unroll
      for (int i=0;i<4;i++){
        float4 v = mrow[sub + 8*i];
        float4 kk = wk4[sub + 8*i];
        ss += v.x*v.x + v.y*v.y + v.z*v.z + v.w*v.w;
        d  += v.x*kk.x + v.y*kk.y + v.z*kk.z + v.w*kk.w;
      }
      #pragma unroll
      for (int off=4; off>0; off>>=1){
        ss += __shfl_down(ss,off,8);
        d  += __shfl_down(d, off,8);
      }
      if (sub==0){ memnorm[row] = 1.0f/(sqrtf(ss)+DELTA); wcw[row] = d; }
    }
    if (tid < M){   // usage update (prev ww, prev rw)
      float um = usage[tid] + (1.0f-usage[tid])*ww[tid];
      float psi = 1.0f;
      #pragma unroll
      for (int r=0;r<RH;r++) psi *= (1.0f - fg[r]*rw[r*M+tid]);
      usage[tid] = um*psi;
    }
    if (wave == 0){
      float v0 = wk[lane], v1 = wk[lane+64];
      float ss = waveAllSum(v0*v0+v1*v1);
      if (lane==0) s_wkinv = 1.0f/(sqrtf(ss)+DELTA);
    } else if (wave <= RH){
      int r = wave-1;
      float v0 = rk[r*W+lane], v1 = rk[r*W+lane+64];
      float ss = waveAllSum(v0*v0+v1*v1);
      if (lane==0) s_rkinv[r] = 1.0f/(sqrtf(ss)+DELTA);
    }
    __syncthreads();

    // ===== Phase D: wave0 = scale+softmax(wcw); wave1 = allocation sort ======
    if (wave == 0){
      float x = wcw[lane] * memnorm[lane] * s_wkinv * s_wstr;
      float mx = waveAllMax(x);
      float e = expf(x-mx);
      float s = waveAllSum(e);
      wcw[lane] = e/s;
    } else if (wave == 1){
      float u = DELTA + (1.0f-DELTA)*usage[lane];
      int idx = lane;
      for (int k=2;k<=64;k<<=1){
        for (int j=k>>1;j>0;j>>=1){
          float ou = __shfl_xor(u, j, 64);
          int   oi = __shfl_xor(idx, j, 64);
          bool up = ((lane & k) == 0);
          bool iLower = ((lane & j) == 0);
          bool otherLess = (ou < u) || (ou == u && oi < idx);
          bool takeOther = (up == iLower) ? otherLess : !otherLess;
          if (takeOther){ u = ou; idx = oi; }
        }
      }
      float p = u;
      for (int d=1; d<64; d<<=1){
        float pv = __shfl_up(p, d, 64);
        if (lane >= d) p *= pv;
      }
      float ep = __shfl_up(p, 1, 64);
      if (lane == 0) ep = 1.0f;
      alloc_s[idx] = (1.0f - u) * ep;
    }
    __syncthreads();

    // ===== Phase F: mem write + link update, ww computed on the fly ==========
    {
      const float cg = s_wg, ag = s_ag;
      #pragma unroll
      for (int e=0;e<16;e++){
        int f = tid + 512*e;
        int m = f >> 7, w = f & 127;
        float wwm = cg*(ag*alloc_s[m] + (1.0f-ag)*wcw[m]);
        mem[m*MEMLD+w] = mem[m*MEMLD+w]*(1.0f - wwm*er[w]) + wwm*wv[w];
      }
      #pragma unroll
      for (int e=0;e<8;e++){
        int f = tid + 512*e;
        int i = f >> 6, j = f & 63;
        float wwi = cg*(ag*alloc_s[i] + (1.0f-ag)*wcw[i]);
        float wwj = cg*(ag*alloc_s[j] + (1.0f-ag)*wcw[j]);
        float lv = (1.0f - wwi - wwj)*link[i*LNKLD+j] + wwi*prec[j];
        link[i*LNKLD+j] = (i==j) ? 0.0f : lv;
      }
      if (tid < M) ww[tid] = cg*(ag*alloc_s[tid] + (1.0f-ag)*wcw[tid]);
    }
    __syncthreads();

    // ===== Phase GHJ: post-norms + RAW read dots (one mem scan, 4 heads),
    //       fwd/bwd via link, wwsum — one barrier ============================
    {
      int row = tid >> 3, sub = tid & 7;
      const float4* mrow = (const float4*)(mem + row*MEMLD);
      const float4* rk4  = (const float4*)rk;
      float ss=0.f, d0=0.f, d1=0.f, d2=0.f, d3=0.f;
      #pragma unroll
      for (int i=0;i<4;i++){
        int e4 = sub + 8*i;
        float4 v = mrow[e4];
        float4 k0 = rk4[e4];
        float4 k1 = rk4[32+e4];
        float4 k2 = rk4[64+e4];
        float4 k3 = rk4[96+e4];
        ss += v.x*v.x + v.y*v.y + v.z*v.z + v.w*v.w;
        d0 += v.x*k0.x + v.y*k0.y + v.z*k0.z + v.w*k0.w;
        d1 += v.x*k1.x + v.y*k1.y + v.z*k1.z + v.w*k1.w;
        d2 += v.x*k2.x + v.y*k2.y + v.z*k2.z + v.w*k2.w;
        d3 += v.x*k3.x + v.y*k3.y + v.z*k3.z + v.w*k3.w;
      }
      #pragma unroll
      for (int off=4; off>0; off>>=1){
        ss += __shfl_down(ss,off,8);
        d0 += __shfl_down(d0,off,8);
        d1 += __shfl_down(d1,off,8);
        d2 += __shfl_down(d2,off,8);
        d3 += __shfl_down(d3,off,8);
      }
      if (sub==0){
        memnorm[row] = 1.0f/(sqrtf(ss)+DELTA);
        cwm[row] = d0; cwm[M+row] = d1; cwm[2*M+row] = d2; cwm[3*M+row] = d3;
      }
    }
    // fwd/bwd via link (old rw)
    if (tid < 256){
      int r = tid >> 6, i = tid & 63;
      float a = 0.f;
      #pragma unroll 8
      for (int j=0;j<M;j++) a += link[i*LNKLD+j]*rw[r*M+j];
      fwd[r*M+i] = a;
    } else {
      int q = tid - 256;
      int r = q >> 6, j = q & 63;
      float a = 0.f;
      #pragma unroll 8
      for (int i=0;i<M;i++) a += rw[r*M+i]*link[i*LNKLD+j];
      bwd[r*M+j] = a;
    }
    if (wave == 7){
      float s = waveAllSum(ww[lane]);
      if (lane==0) s_wwsum = s;
    }
    __syncthreads();

    // ===== Phase IK: scale+softmax read scores AND rw update (cwm in regs);
    //       prec update on wave 4 ===========================================
    if (wave < RH){
      int r = wave;
      float x = cwm[r*M + lane] * memnorm[lane] * s_rkinv[r] * rstr[r];
      float mx = waveAllMax(x);
      float e = expf(x-mx);
      float s = waveAllSum(e);
      float c = e/s;
      rw[r*M+lane] = rmode[3*r]*bwd[r*M+lane] + rmode[3*r+1]*fwd[r*M+lane]
                   + rmode[3*r+2]*c;
    } else if (wave == 4){
      prec[lane] = (1.0f - s_wwsum)*prec[lane] + ww[lane];
    }
    __syncthreads();

    // ===== Phase L: read vectors -> stash (no trailing barrier; next phase
    //       only writes gates[], disjoint from mem/rw reads here) ============
    {
      int r = tid >> 7, w = tid & 127;
      float a = 0.f;
      #pragma unroll 8
      for (int m=0;m<M;m++) a += rw[r*M+m]*mem[m*MEMLD+w];
      stash[bt*640 + 128 + tid] = a;
    }
  }
}

extern "C" void kernel_launch(void* const* d_in, const int* in_sizes, int n_in,
                              void* d_out, int out_size, void* d_ws, size_t ws_size,
                              hipStream_t stream)
{
  const int*   tokens  = (const int*)d_in[0];
  const float* emb     = (const float*)d_in[1];
  const float* w_ih0   = (const float*)d_in[2];
  const float* w_hh0   = (const float*)d_in[3];
  const float* b_ih0   = (const float*)d_in[4];
  const float* b_hh0   = (const float*)d_in[5];
  const float* w_ih1   = (const float*)d_in[6];
  const float* w_hh1   = (const float*)d_in[7];
  const float* b_ih1   = (const float*)d_in[8];
  const float* b_hh1   = (const float*)d_in[9];
  const float* w_iface = (const float*)d_in[10];
  const float* b_iface = (const float*)d_in[11];
  const float* w_out   = (const float*)d_in[12];
  const float* b_out   = (const float*)d_in[13];
  const float* w_fc    = (const float*)d_in[14];
  const float* b_fc    = (const float*)d_in[15];
  const float* h0      = (const float*)d_in[16];
  float* out = (float*)d_out;
  float* ws  = (float*)d_ws;

  float* xw0     = ws;                   // 512*512    = 262144
  float* whh0T   = xw0     + 262144;     // 128*512    = 65536
  float* w1catT  = whh0T   + 65536;      // 256*512    = 131072
  float* wifaceT = w1catT  + 131072;     // 128*919    = 117632
  float* wih0T   = wifaceT + 117632;     // 128*512    = 65536 (temp for xw0)
  float* stash   = wih0T   + 65536;      // 16384*640  = 10485760
  // total ~11.1M floats = 44.5 MB (fits: R2 verified ws_size >= 52.8 MB)

  auto tp = [&](const float* in, float* o, int rows, int cols, int use){
    int total = rows*use;
    k_transpose<<<(total+255)/256, 256, 0, stream>>>(in, o, rows, cols, use);
  };
  tp(w_ih0,   wih0T,          512, 640, 128);
  tp(w_hh0,   whh0T,          512, 128, 128);
  tp(w_ih1,   w1catT,         512, 128, 128);
  tp(w_hh1,   w1catT+128*G4,  512, 128, 128);
  tp(w_iface, wifaceT,        919, 128, 128);
  k_xw0<<<VOCAB, 512, 0, stream>>>(emb, wih0T, b_ih0, b_hh0, xw0);
  k_dnc<<<B, 512, 0, stream>>>(tokens, xw0, whh0T, w1catT, b_ih1, b_hh1,
                               wifaceT, b_iface, h0, stash);
  k_tail<<<(B*T)/32, 512, 0, stream>>>(stash, w_out, b_out, w_fc, b_fc, out);
}

// Round 6
// 7573.198 us; speedup vs baseline: 2.2330x; 2.2330x over previous
//
#include <hip/hip_runtime.h>
#include <math.h>

#define B 128
#define T 128
#define H 128
#define RH 4
#define M 64
#define W 128
#define VOCAB 512
#define IFACE 919
#define G4 512
#define DELTA 1e-6f
#define CLIPV 20.0f

#define MEMLD 132   // mem row stride (W=128 + 4) -> 528B rows, 16B aligned
#define LNKLD 67    // link row stride (M=64 + 3)

__device__ __forceinline__ float sigmoidf_(float x){ return 1.0f/(1.0f+expf(-x)); }
__device__ __forceinline__ float softplusf_(float x){
  return fmaxf(x, 0.0f) + log1pf(expf(-fabsf(x)));
}
__device__ __forceinline__ float waveAllSum(float v){
  for (int off=1; off<64; off<<=1) v += __shfl_xor(v, off, 64);
  return v;
}
__device__ __forceinline__ float waveAllMax(float v){
  for (int off=1; off<64; off<<=1) v = fmaxf(v, __shfl_xor(v, off, 64));
  return v;
}

__global__ void k_transpose(const float* __restrict__ in, float* __restrict__ out,
                            int rows, int cols, int use_cols){
  int idx = blockIdx.x*blockDim.x + threadIdx.x;
  int total = rows*use_cols;
  if (idx < total){
    int r = idx / use_cols, c = idx - r*use_cols;
    out[c*rows + r] = in[r*cols + c];
  }
}

// xw0[v][g] = emb[v]·w_ih0[g][0:128] + b_ih0[g] + b_hh0[g]  (coalesced via wih0T)
__global__ void k_xw0(const float* __restrict__ emb, const float* __restrict__ wih0T,
                      const float* __restrict__ b_ih0, const float* __restrict__ b_hh0,
                      float* __restrict__ xw0){
  __shared__ float e[H];
  int v = blockIdx.x, g = threadIdx.x;
  if (g < H) e[g] = emb[v*H + g];
  __syncthreads();
  float acc = b_ih0[g] + b_hh0[g];
  #pragma unroll 8
  for (int k=0;k<H;k++) acc += e[k]*wih0T[k*G4 + g];
  xw0[v*G4 + g] = acc;
}

// fused tail: per 32 (b,t) rows -> Y = stash·w_out^T + b_out -> logits -> out
__launch_bounds__(512, 1)
__global__ void k_tail(const float* __restrict__ stash, const float* __restrict__ w_out,
                       const float* __restrict__ b_out, const float* __restrict__ w_fc,
                       const float* __restrict__ b_fc, float* __restrict__ out){
  __shared__ __align__(16) float S[32*644];
  __shared__ float Y[32*129];
  const int tid = threadIdx.x;
  const long bt0 = (long)blockIdx.x*32;

  for (int idx = tid; idx < 32*640; idx += 512){
    int bt = idx / 640, k = idx - bt*640;
    S[bt*644 + k] = stash[(bt0+bt)*640 + k];
  }
  __syncthreads();
  { // Y[bt][o]
    int og = tid >> 5, bt = tid & 31;
    const float4* s4 = (const float4*)(S + bt*644);
    #pragma unroll
    for (int oo = 0; oo < 8; ++oo){
      int o = og*8 + oo;
      const float4* w4 = (const float4*)(w_out + (size_t)o*640);
      float acc = b_out[o];
      #pragma unroll 8
      for (int k4 = 0; k4 < 160; ++k4){
        float4 w = w4[k4], s = s4[k4];
        acc += w.x*s.x + w.y*s.y + w.z*s.z + w.w*s.w;
      }
      Y[bt*129 + o] = acc;
    }
  }
  __syncthreads();
  { // logits, coalesced on t
    int t = tid & 31, vg = tid >> 5;
    int b  = (int)(bt0 >> 7);
    int tb = (int)(bt0 & 127);
    const float* yr = Y + t*129;
    #pragma unroll 2
    for (int vv = 0; vv < 32; ++vv){
      int v = vg*32 + vv;
      const float4* w4 = (const float4*)(w_fc + (size_t)v*H);
      float acc = b_fc[v];
      #pragma unroll 8
      for (int k4 = 0; k4 < 32; ++k4){
        float4 w = w4[k4];
        int k = k4*4;
        acc += w.x*yr[k] + w.y*yr[k+1] + w.z*yr[k+2] + w.w*yr[k+3];
      }
      out[((size_t)b*VOCAB + v)*T + tb + t] = acc;
    }
  }
}

__launch_bounds__(512, 1)
__global__ void k_dnc(const int* __restrict__ tokens,
                      const float* __restrict__ xw0,
                      const float* __restrict__ whh0T,
                      const float* __restrict__ w1catT,
                      const float* __restrict__ b_ih1,
                      const float* __restrict__ b_hh1,
                      const float* __restrict__ wifaceT,
                      const float* __restrict__ b_iface,
                      const float* __restrict__ h0,
                      float* __restrict__ stash)
{
  const int b = blockIdx.x;
  const int tid = threadIdx.x;
  const int lane = tid & 63;
  const int wave = tid >> 6;

  __shared__ __align__(16) float hcat[2*H];           // h0 || h1
  __shared__ __align__(16) float c0s[H], c1s[H], outv[H];
  __shared__ __align__(16) float mem[M*MEMLD];
  __shared__ float link[M*LNKLD];
  __shared__ float prec[M], ww[M], usage[M];
  __shared__ float rw[RH*M];
  __shared__ __align__(16) float gates[G4];
  __shared__ __align__(16) float xi[920];
  __shared__ __align__(16) float rk[RH*W];
  __shared__ __align__(16) float wk[W];
  __shared__ float er[W], wv[W];
  __shared__ float memnorm[M];
  __shared__ float wcw[M], alloc_s[M];
  __shared__ float cwm[RH*M], fwd[RH*M], bwd[RH*M];
  __shared__ int   tok[T];
  __shared__ float rstr[RH], fg[RH], rmode[RH*3];
  __shared__ float s_wstr, s_ag, s_wg, s_wwsum, s_wkinv, s_rkinv[RH];

  // loop-invariant hoist (LSTM1 bias)
  const float b1sum = b_ih1[tid] + b_hh1[tid];

  if (tid < H){
    float hv0 = h0[0*B*H + b*H + tid];
    float hv1 = h0[1*B*H + b*H + tid];
    hcat[tid]=hv0; hcat[H+tid]=hv1; c0s[tid]=hv0; c1s[tid]=hv1;
  }
  if (tid < T) tok[tid] = tokens[b*T + tid];
  for (int i = tid; i < M*MEMLD; i += 512) mem[i]=0.f;
  for (int i = tid; i < M*LNKLD; i += 512) link[i]=0.f;
  if (tid < M){ prec[tid]=0.f; ww[tid]=0.f; usage[tid]=0.f; }
  if (tid < RH*M) rw[tid]=0.f;
  __syncthreads();

  for (int t = 0; t < T; ++t){
    const long bt = (long)b*T + t;

    // ====== mv0: gates = xw0[token] + w_hh0^T·h0  (R1-proven pattern) =======
    {
      float acc = xw0[(size_t)tok[t]*G4 + tid];
      const float* wp = whh0T + tid;
      #pragma unroll 8
      for (int k=0;k<H;k++) acc += hcat[k]*wp[k*G4];
      gates[tid] = acc;
    }
    __syncthreads();
    // ---- pw0
    if (tid < H){
      float ig = sigmoidf_(gates[tid]);
      float ff = sigmoidf_(gates[H+tid]);
      float gg = tanhf(gates[2*H+tid]);
      float og = sigmoidf_(gates[3*H+tid]);
      float c2 = ff*c0s[tid] + ig*gg;
      c0s[tid] = c2;
      hcat[tid] = og*tanhf(c2);
    }
    __syncthreads();

    // ====== mv1: gates = b1 + w_ih1^T·h0 + w_hh1^T·h1  (R1 pattern) =========
    {
      float acc = b1sum;
      const float* wp1 = w1catT + tid;            // k in [0,128)   -> w_ih1
      const float* wp2 = w1catT + 128*G4 + tid;   // k in [128,256) -> w_hh1
      #pragma unroll 4
      for (int k=0;k<H;k++) acc += hcat[k]*wp1[k*G4] + hcat[H+k]*wp2[k*G4];
      gates[tid] = acc;
    }
    __syncthreads();
    // ---- pw1 (+ stash first 128)
    if (tid < H){
      float ig = sigmoidf_(gates[tid]);
      float ff = sigmoidf_(gates[H+tid]);
      float gg = tanhf(gates[2*H+tid]);
      float og = sigmoidf_(gates[3*H+tid]);
      float c2 = ff*c1s[tid] + ig*gg;
      c1s[tid] = c2;
      float h2 = og*tanhf(c2);
      hcat[H+tid] = h2;
      float ov = fminf(fmaxf(h2, -CLIPV), CLIPV);
      outv[tid] = ov;
      stash[bt*640 + tid] = ov;
    }
    __syncthreads();

    // ====== iface: xi = w_iface^T·outv + b_iface  (R1-proven pattern) =======
    for (int j = tid; j < IFACE; j += 512){
      float acc = b_iface[j];
      const float* wp = wifaceT + j;
      #pragma unroll 8
      for (int k=0;k<H;k++) acc += outv[k]*wp[k*IFACE];
      xi[j] = acc;
    }
    __syncthreads();

    // ================= parse interface =======================================
    rk[tid] = tanhf(xi[tid]);
    if (tid < W){
      wk[tid] = tanhf(xi[516+tid]);
      er[tid] = sigmoidf_(xi[645+tid]);
      wv[tid] = tanhf(xi[773+tid]);
    }
    if (tid < RH){
      rstr[tid] = softplusf_(xi[512+tid]);
      fg[tid]   = sigmoidf_(xi[901+tid]);
      float a0 = xi[907+3*tid], a1 = xi[908+3*tid], a2 = xi[909+3*tid];
      float mx = fmaxf(a0, fmaxf(a1,a2));
      float e0=expf(a0-mx), e1=expf(a1-mx), e2=expf(a2-mx);
      float s = e0+e1+e2;
      rmode[3*tid]=e0/s; rmode[3*tid+1]=e1/s; rmode[3*tid+2]=e2/s;
    }
    if (tid == 0){
      s_wstr = softplusf_(xi[644]);
      s_ag = sigmoidf_(xi[905]);
      s_wg = sigmoidf_(xi[906]);
    }
    __syncthreads();

    // ===== Phase ABC: pre-norms + write-content dots (one mem scan),
    //       usage update, key norms — one barrier ============================
    {
      int row = tid >> 3, sub = tid & 7;
      const float4* mrow = (const float4*)(mem + row*MEMLD);
      const float4* wk4  = (const float4*)wk;
      float ss=0.f, d=0.f;
      #pragma unroll
      for (int i=0;i<4;i++){
        float4 v = mrow[sub + 8*i];
        float4 kk = wk4[sub + 8*i];
        ss += v.x*v.x + v.y*v.y + v.z*v.z + v.w*v.w;
        d  += v.x*kk.x + v.y*kk.y + v.z*kk.z + v.w*kk.w;
      }
      #pragma unroll
      for (int off=4; off>0; off>>=1){
        ss += __shfl_down(ss,off,8);
        d  += __shfl_down(d, off,8);
      }
      if (sub==0){ memnorm[row] = 1.0f/(sqrtf(ss)+DELTA); wcw[row] = d; }
    }
    if (tid < M){   // usage update (prev ww, prev rw)
      float um = usage[tid] + (1.0f-usage[tid])*ww[tid];
      float psi = 1.0f;
      #pragma unroll
      for (int r=0;r<RH;r++) psi *= (1.0f - fg[r]*rw[r*M+tid]);
      usage[tid] = um*psi;
    }
    if (wave == 0){
      float v0 = wk[lane], v1 = wk[lane+64];
      float ss = waveAllSum(v0*v0+v1*v1);
      if (lane==0) s_wkinv = 1.0f/(sqrtf(ss)+DELTA);
    } else if (wave <= RH){
      int r = wave-1;
      float v0 = rk[r*W+lane], v1 = rk[r*W+lane+64];
      float ss = waveAllSum(v0*v0+v1*v1);
      if (lane==0) s_rkinv[r] = 1.0f/(sqrtf(ss)+DELTA);
    }
    __syncthreads();

    // ===== Phase D: wave0 = scale+softmax(wcw); wave1 = allocation sort ======
    if (wave == 0){
      float x = wcw[lane] * memnorm[lane] * s_wkinv * s_wstr;
      float mx = waveAllMax(x);
      float e = expf(x-mx);
      float s = waveAllSum(e);
      wcw[lane] = e/s;
    } else if (wave == 1){
      float u = DELTA + (1.0f-DELTA)*usage[lane];
      int idx = lane;
      for (int k=2;k<=64;k<<=1){
        for (int j=k>>1;j>0;j>>=1){
          float ou = __shfl_xor(u, j, 64);
          int   oi = __shfl_xor(idx, j, 64);
          bool up = ((lane & k) == 0);
          bool iLower = ((lane & j) == 0);
          bool otherLess = (ou < u) || (ou == u && oi < idx);
          bool takeOther = (up == iLower) ? otherLess : !otherLess;
          if (takeOther){ u = ou; idx = oi; }
        }
      }
      float p = u;
      for (int d=1; d<64; d<<=1){
        float pv = __shfl_up(p, d, 64);
        if (lane >= d) p *= pv;
      }
      float ep = __shfl_up(p, 1, 64);
      if (lane == 0) ep = 1.0f;
      alloc_s[idx] = (1.0f - u) * ep;
    }
    __syncthreads();

    // ===== Phase F: mem write + link update, ww computed on the fly ==========
    {
      const float cg = s_wg, ag = s_ag;
      #pragma unroll
      for (int e=0;e<16;e++){
        int f = tid + 512*e;
        int m = f >> 7, w = f & 127;
        float wwm = cg*(ag*alloc_s[m] + (1.0f-ag)*wcw[m]);
        mem[m*MEMLD+w] = mem[m*MEMLD+w]*(1.0f - wwm*er[w]) + wwm*wv[w];
      }
      #pragma unroll
      for (int e=0;e<8;e++){
        int f = tid + 512*e;
        int i = f >> 6, j = f & 63;
        float wwi = cg*(ag*alloc_s[i] + (1.0f-ag)*wcw[i]);
        float wwj = cg*(ag*alloc_s[j] + (1.0f-ag)*wcw[j]);
        float lv = (1.0f - wwi - wwj)*link[i*LNKLD+j] + wwi*prec[j];
        link[i*LNKLD+j] = (i==j) ? 0.0f : lv;
      }
      if (tid < M) ww[tid] = cg*(ag*alloc_s[tid] + (1.0f-ag)*wcw[tid]);
    }
    __syncthreads();

    // ===== Phase GHJ: post-norms + read dots (one mem scan, 4 heads),
    //       fwd/bwd via link, wwsum — one barrier ============================
    {
      int row = tid >> 3, sub = tid & 7;
      const float4* mrow = (const float4*)(mem + row*MEMLD);
      const float4* rk4  = (const float4*)rk;
      float ss=0.f, d0=0.f, d1=0.f, d2=0.f, d3=0.f;
      #pragma unroll
      for (int i=0;i<4;i++){
        int e4 = sub + 8*i;
        float4 v = mrow[e4];
        float4 k0 = rk4[e4];
        float4 k1 = rk4[32+e4];
        float4 k2 = rk4[64+e4];
        float4 k3 = rk4[96+e4];
        ss += v.x*v.x + v.y*v.y + v.z*v.z + v.w*v.w;
        d0 += v.x*k0.x + v.y*k0.y + v.z*k0.z + v.w*k0.w;
        d1 += v.x*k1.x + v.y*k1.y + v.z*k1.z + v.w*k1.w;
        d2 += v.x*k2.x + v.y*k2.y + v.z*k2.z + v.w*k2.w;
        d3 += v.x*k3.x + v.y*k3.y + v.z*k3.z + v.w*k3.w;
      }
      #pragma unroll
      for (int off=4; off>0; off>>=1){
        ss += __shfl_down(ss,off,8);
        d0 += __shfl_down(d0,off,8);
        d1 += __shfl_down(d1,off,8);
        d2 += __shfl_down(d2,off,8);
        d3 += __shfl_down(d3,off,8);
      }
      if (sub==0){
        memnorm[row] = 1.0f/(sqrtf(ss)+DELTA);
        cwm[row] = d0; cwm[M+row] = d1; cwm[2*M+row] = d2; cwm[3*M+row] = d3;
      }
    }
    // fwd/bwd via link (old rw)
    if (tid < 256){
      int r = tid >> 6, i = tid & 63;
      float a = 0.f;
      #pragma unroll 8
      for (int j=0;j<M;j++) a += link[i*LNKLD+j]*rw[r*M+j];
      fwd[r*M+i] = a;
    } else {
      int q = tid - 256;
      int r = q >> 6, j = q & 63;
      float a = 0.f;
      #pragma unroll 8
      for (int i=0;i<M;i++) a += rw[r*M+i]*link[i*LNKLD+j];
      bwd[r*M+j] = a;
    }
    if (wave == 7){
      float s = waveAllSum(ww[lane]);
      if (lane==0) s_wwsum = s;
    }
    __syncthreads();

    // ===== Phase IK: scale+softmax read scores AND rw update;
    //       prec update on wave 4 ===========================================
    if (wave < RH){
      int r = wave;
      float x = cwm[r*M + lane] * memnorm[lane] * s_rkinv[r] * rstr[r];
      float mx = waveAllMax(x);
      float e = expf(x-mx);
      float s = waveAllSum(e);
      float c = e/s;
      rw[r*M+lane] = rmode[3*r]*bwd[r*M+lane] + rmode[3*r+1]*fwd[r*M+lane]
                   + rmode[3*r+2]*c;
    } else if (wave == 4){
      prec[lane] = (1.0f - s_wwsum)*prec[lane] + ww[lane];
    }
    __syncthreads();

    // ===== Phase L: read vectors -> stash (no trailing barrier; next phase
    //       only writes gates[], disjoint from mem/rw reads here) ============
    {
      int r = tid >> 7, w = tid & 127;
      float a = 0.f;
      #pragma unroll 8
      for (int m=0;m<M;m++) a += rw[r*M+m]*mem[m*MEMLD+w];
      stash[bt*640 + 128 + tid] = a;
    }
  }
}

extern "C" void kernel_launch(void* const* d_in, const int* in_sizes, int n_in,
                              void* d_out, int out_size, void* d_ws, size_t ws_size,
                              hipStream_t stream)
{
  const int*   tokens  = (const int*)d_in[0];
  const float* emb     = (const float*)d_in[1];
  const float* w_ih0   = (const float*)d_in[2];
  const float* w_hh0   = (const float*)d_in[3];
  const float* b_ih0   = (const float*)d_in[4];
  const float* b_hh0   = (const float*)d_in[5];
  const float* w_ih1   = (const float*)d_in[6];
  const float* w_hh1   = (const float*)d_in[7];
  const float* b_ih1   = (const float*)d_in[8];
  const float* b_hh1   = (const float*)d_in[9];
  const float* w_iface = (const float*)d_in[10];
  const float* b_iface = (const float*)d_in[11];
  const float* w_out   = (const float*)d_in[12];
  const float* b_out   = (const float*)d_in[13];
  const float* w_fc    = (const float*)d_in[14];
  const float* b_fc    = (const float*)d_in[15];
  const float* h0      = (const float*)d_in[16];
  float* out = (float*)d_out;
  float* ws  = (float*)d_ws;

  float* xw0     = ws;                   // 512*512    = 262144
  float* whh0T   = xw0     + 262144;     // 128*512    = 65536
  float* w1catT  = whh0T   + 65536;      // 256*512    = 131072
  float* wifaceT = w1catT  + 131072;     // 128*919    = 117632
  float* wih0T   = wifaceT + 117632;     // 128*512    = 65536 (temp for xw0)
  float* stash   = wih0T   + 65536;      // 16384*640  = 10485760
  // total ~11.1M floats = 44.5 MB (fits: R2 verified ws_size >= 52.8 MB)

  auto tp = [&](const float* in, float* o, int rows, int cols, int use){
    int total = rows*use;
    k_transpose<<<(total+255)/256, 256, 0, stream>>>(in, o, rows, cols, use);
  };
  tp(w_ih0,   wih0T,          512, 640, 128);
  tp(w_hh0,   whh0T,          512, 128, 128);
  tp(w_ih1,   w1catT,         512, 128, 128);
  tp(w_hh1,   w1catT+128*G4,  512, 128, 128);
  tp(w_iface, wifaceT,        919, 128, 128);
  k_xw0<<<VOCAB, 512, 0, stream>>>(emb, wih0T, b_ih0, b_hh0, xw0);
  k_dnc<<<B, 512, 0, stream>>>(tokens, xw0, whh0T, w1catT, b_ih1, b_hh1,
                               wifaceT, b_iface, h0, stash);
  k_tail<<<(B*T)/32, 512, 0, stream>>>(stash, w_out, b_out, w_fc, b_fc, out);
}

// Round 7
// 3479.025 us; speedup vs baseline: 4.8608x; 2.1768x over previous
//
#include <hip/hip_runtime.h>
#include <math.h>

#define B 128
#define T 128
#define H 128
#define RH 4
#define M 64
#define W 128
#define VOCAB 512
#define IFACE 919
#define G4 512
#define DELTA 1e-6f
#define CLIPV 20.0f

#define MEMLD 132   // mem row stride (W=128 + 4)
#define LNKLD 67    // link row stride (M=64 + 3)

__device__ __forceinline__ float sigmoidf_(float x){ return 1.0f/(1.0f+expf(-x)); }
__device__ __forceinline__ float softplusf_(float x){
  return fmaxf(x, 0.0f) + log1pf(expf(-fabsf(x)));
}
__device__ __forceinline__ float waveAllSum(float v){
  for (int off=1; off<64; off<<=1) v += __shfl_xor(v, off, 64);
  return v;
}
__device__ __forceinline__ float waveAllMax(float v){
  for (int off=1; off<64; off<<=1) v = fmaxf(v, __shfl_xor(v, off, 64));
  return v;
}

__global__ void k_transpose(const float* __restrict__ in, float* __restrict__ out,
                            int rows, int cols, int use_cols){
  int idx = blockIdx.x*blockDim.x + threadIdx.x;
  int total = rows*use_cols;
  if (idx < total){
    int r = idx / use_cols, c = idx - r*use_cols;
    out[c*rows + r] = in[r*cols + c];
  }
}

// xw0[v][g] = emb[v]·w_ih0[g][0:128] + b_ih0[g] + b_hh0[g]  (coalesced via wih0T)
__global__ void k_xw0(const float* __restrict__ emb, const float* __restrict__ wih0T,
                      const float* __restrict__ b_ih0, const float* __restrict__ b_hh0,
                      float* __restrict__ xw0){
  __shared__ float e[H];
  int v = blockIdx.x, g = threadIdx.x;
  if (g < H) e[g] = emb[v*H + g];
  __syncthreads();
  float acc = b_ih0[g] + b_hh0[g];
  #pragma unroll 8
  for (int k=0;k<H;k++) acc += e[k]*wih0T[k*G4 + g];
  xw0[v*G4 + g] = acc;
}

// fused tail: per 32 (b,t) rows -> Y = stash·w_out^T + b_out -> logits -> out
__launch_bounds__(512, 1)
__global__ void k_tail(const float* __restrict__ stash, const float* __restrict__ w_out,
                       const float* __restrict__ b_out, const float* __restrict__ w_fc,
                       const float* __restrict__ b_fc, float* __restrict__ out){
  __shared__ __align__(16) float S[32*644];
  __shared__ float Y[32*129];
  const int tid = threadIdx.x;
  const long bt0 = (long)blockIdx.x*32;

  for (int idx = tid; idx < 32*640; idx += 512){
    int bt = idx / 640, k = idx - bt*640;
    S[bt*644 + k] = stash[(bt0+bt)*640 + k];
  }
  __syncthreads();
  { // Y[bt][o]
    int og = tid >> 5, bt = tid & 31;
    const float4* s4 = (const float4*)(S + bt*644);
    #pragma unroll
    for (int oo = 0; oo < 8; ++oo){
      int o = og*8 + oo;
      const float4* w4 = (const float4*)(w_out + (size_t)o*640);
      float acc = b_out[o];
      #pragma unroll 8
      for (int k4 = 0; k4 < 160; ++k4){
        float4 w = w4[k4], s = s4[k4];
        acc += w.x*s.x + w.y*s.y + w.z*s.z + w.w*s.w;
      }
      Y[bt*129 + o] = acc;
    }
  }
  __syncthreads();
  { // logits, coalesced on t
    int t = tid & 31, vg = tid >> 5;
    int b  = (int)(bt0 >> 7);
    int tb = (int)(bt0 & 127);
    const float* yr = Y + t*129;
    #pragma unroll 2
    for (int vv = 0; vv < 32; ++vv){
      int v = vg*32 + vv;
      const float4* w4 = (const float4*)(w_fc + (size_t)v*H);
      float acc = b_fc[v];
      #pragma unroll 8
      for (int k4 = 0; k4 < 32; ++k4){
        float4 w = w4[k4];
        int k = k4*4;
        acc += w.x*yr[k] + w.y*yr[k+1] + w.z*yr[k+2] + w.w*yr[k+3];
      }
      out[((size_t)b*VOCAB + v)*T + tb + t] = acc;
    }
  }
}

__launch_bounds__(512, 1)
__global__ void k_dnc(const int* __restrict__ tokens,
                      const float* __restrict__ xw0,
                      const float* __restrict__ whh0T,
                      const float* __restrict__ w1catT,
                      const float* __restrict__ b_ih1,
                      const float* __restrict__ b_hh1,
                      const float* __restrict__ wifaceT,
                      const float* __restrict__ b_iface,
                      const float* __restrict__ h0,
                      float* __restrict__ stash)
{
  const int b = blockIdx.x;
  const int tid = threadIdx.x;
  const int lane = tid & 63;
  const int wave = tid >> 6;

  __shared__ __align__(16) float hcat[2*H];           // h0 || h1
  __shared__ __align__(16) float c0s[H], c1s[H], outv[H];
  __shared__ __align__(16) float mem[M*MEMLD];
  __shared__ float link[M*LNKLD];
  __shared__ float prec[M], ww[M], usage[M];
  __shared__ float rw[RH*M];
  __shared__ __align__(16) float gates[G4];
  __shared__ __align__(16) float xi[920];
  __shared__ __align__(16) float rk[RH*W];
  __shared__ float wk[W], er[W], wv[W];
  __shared__ float memnorm[M];
  __shared__ float wcw[M], alloc_s[M];
  __shared__ float cwm[RH*M], fwd[RH*M], bwd[RH*M];
  __shared__ int   tok[T];
  __shared__ float rstr[RH], fg[RH], rmode[RH*3];
  __shared__ float s_wstr, s_ag, s_wg, s_wwsum, s_wkinv, s_rkinv[RH];

  // loop-invariant hoist (LSTM1 bias)
  const float b1sum = b_ih1[tid] + b_hh1[tid];

  if (tid < H){
    float hv0 = h0[0*B*H + b*H + tid];
    float hv1 = h0[1*B*H + b*H + tid];
    hcat[tid]=hv0; hcat[H+tid]=hv1; c0s[tid]=hv0; c1s[tid]=hv1;
  }
  if (tid < T) tok[tid] = tokens[b*T + tid];
  for (int i = tid; i < M*MEMLD; i += 512) mem[i]=0.f;
  for (int i = tid; i < M*LNKLD; i += 512) link[i]=0.f;
  if (tid < M){ prec[tid]=0.f; ww[tid]=0.f; usage[tid]=0.f; }
  if (tid < RH*M) rw[tid]=0.f;
  __syncthreads();

  for (int t = 0; t < T; ++t){
    const long bt = (long)b*T + t;

    // ====== mv0: gates = xw0[token] + w_hh0^T·h0  (R1-proven pattern) =======
    {
      float acc = xw0[(size_t)tok[t]*G4 + tid];
      const float* wp = whh0T + tid;
      #pragma unroll 8
      for (int k=0;k<H;k++) acc += hcat[k]*wp[k*G4];
      gates[tid] = acc;
    }
    __syncthreads();
    // ---- pw0
    if (tid < H){
      float ig = sigmoidf_(gates[tid]);
      float ff = sigmoidf_(gates[H+tid]);
      float gg = tanhf(gates[2*H+tid]);
      float og = sigmoidf_(gates[3*H+tid]);
      float c2 = ff*c0s[tid] + ig*gg;
      c0s[tid] = c2;
      hcat[tid] = og*tanhf(c2);
    }
    __syncthreads();

    // ====== mv1: gates = b1 + w_ih1^T·h0 + w_hh1^T·h1  (R1 pattern) =========
    {
      float acc = b1sum;
      const float* wp1 = w1catT + tid;            // k in [0,128)   -> w_ih1
      const float* wp2 = w1catT + 128*G4 + tid;   // k in [128,256) -> w_hh1
      #pragma unroll 4
      for (int k=0;k<H;k++) acc += hcat[k]*wp1[k*G4] + hcat[H+k]*wp2[k*G4];
      gates[tid] = acc;
    }
    __syncthreads();
    // ---- pw1 (+ stash first 128)
    if (tid < H){
      float ig = sigmoidf_(gates[tid]);
      float ff = sigmoidf_(gates[H+tid]);
      float gg = tanhf(gates[2*H+tid]);
      float og = sigmoidf_(gates[3*H+tid]);
      float c2 = ff*c1s[tid] + ig*gg;
      c1s[tid] = c2;
      float h2 = og*tanhf(c2);
      hcat[H+tid] = h2;
      float ov = fminf(fmaxf(h2, -CLIPV), CLIPV);
      outv[tid] = ov;
      stash[bt*640 + tid] = ov;
    }
    __syncthreads();

    // ====== iface: xi = w_iface^T·outv + b_iface  (R1-proven pattern) =======
    for (int j = tid; j < IFACE; j += 512){
      float acc = b_iface[j];
      const float* wp = wifaceT + j;
      #pragma unroll 8
      for (int k=0;k<H;k++) acc += outv[k]*wp[k*IFACE];
      xi[j] = acc;
    }
    __syncthreads();

    // ================= parse interface =======================================
    rk[tid] = tanhf(xi[tid]);
    if (tid < W){
      wk[tid] = tanhf(xi[516+tid]);
      er[tid] = sigmoidf_(xi[645+tid]);
      wv[tid] = tanhf(xi[773+tid]);
    }
    if (tid < RH){
      rstr[tid] = softplusf_(xi[512+tid]);
      fg[tid]   = sigmoidf_(xi[901+tid]);
      float a0 = xi[907+3*tid], a1 = xi[908+3*tid], a2 = xi[909+3*tid];
      float mx = fmaxf(a0, fmaxf(a1,a2));
      float e0=expf(a0-mx), e1=expf(a1-mx), e2=expf(a2-mx);
      float s = e0+e1+e2;
      rmode[3*tid]=e0/s; rmode[3*tid+1]=e1/s; rmode[3*tid+2]=e2/s;
    }
    if (tid == 0){
      s_wstr = softplusf_(xi[644]);
      s_ag = sigmoidf_(xi[905]);
      s_wg = sigmoidf_(xi[906]);
    }
    __syncthreads();

    // ---- Phase A+B: usage update, pre-write mem norms, key norms (R4 exact)
    {
      int row = tid >> 3, sub = tid & 7;
      float ss = 0.f;
      #pragma unroll
      for (int i=0;i<16;i++){ float v = mem[row*MEMLD + sub + 8*i]; ss += v*v; }
      ss += __shfl_down(ss,4,8); ss += __shfl_down(ss,2,8); ss += __shfl_down(ss,1,8);
      if (sub==0) memnorm[row] = 1.0f/(sqrtf(ss)+DELTA);
    }
    if (tid < M){
      float um = usage[tid] + (1.0f-usage[tid])*ww[tid];
      float psi = 1.0f;
      #pragma unroll
      for (int r=0;r<RH;r++) psi *= (1.0f - fg[r]*rw[r*M+tid]);
      usage[tid] = um*psi;
    }
    if (wave == 0){
      float v0 = wk[lane], v1 = wk[lane+64];
      float ss = waveAllSum(v0*v0+v1*v1);
      if (lane==0) s_wkinv = 1.0f/(sqrtf(ss)+DELTA);
    } else if (wave <= RH){
      int r = wave-1;
      float v0 = rk[r*W+lane], v1 = rk[r*W+lane+64];
      float ss = waveAllSum(v0*v0+v1*v1);
      if (lane==0) s_rkinv[r] = 1.0f/(sqrtf(ss)+DELTA);
    }
    __syncthreads();

    // ---- Phase C: write content scores (pre-write memory) (R4 exact)
    {
      int m = tid >> 3, sub = tid & 7;
      float d = 0.f;
      #pragma unroll
      for (int i=0;i<16;i++){ int e = sub + 8*i; d += mem[m*MEMLD + e]*wk[e]; }
      d += __shfl_down(d,4,8); d += __shfl_down(d,2,8); d += __shfl_down(d,1,8);
      if (sub==0) wcw[m] = d * memnorm[m] * s_wkinv * s_wstr;
    }
    __syncthreads();

    // ---- Phase D: wave0 softmax(wcw); wave1 allocation via bitonic argsort
    if (wave == 0){
      float x = wcw[lane];
      float mx = waveAllMax(x);
      float e = expf(x-mx);
      float s = waveAllSum(e);
      wcw[lane] = e/s;
    } else if (wave == 1){
      float u = DELTA + (1.0f-DELTA)*usage[lane];
      int idx = lane;
      for (int k=2;k<=64;k<<=1){
        for (int j=k>>1;j>0;j>>=1){
          float ou = __shfl_xor(u, j, 64);
          int   oi = __shfl_xor(idx, j, 64);
          bool up = ((lane & k) == 0);
          bool iLower = ((lane & j) == 0);
          bool otherLess = (ou < u) || (ou == u && oi < idx);
          bool takeOther = (up == iLower) ? otherLess : !otherLess;
          if (takeOther){ u = ou; idx = oi; }
        }
      }
      float p = u;
      for (int d=1; d<64; d<<=1){
        float pv = __shfl_up(p, d, 64);
        if (lane >= d) p *= pv;
      }
      float ep = __shfl_up(p, 1, 64);
      if (lane == 0) ep = 1.0f;
      alloc_s[idx] = (1.0f - u) * ep;
    }
    __syncthreads();

    // ---- Phase E: write weights + sum
    if (tid < M){
      float wwm = s_wg*(s_ag*alloc_s[tid] + (1.0f-s_ag)*wcw[tid]);
      ww[tid] = wwm;
      float s = waveAllSum(wwm);
      if (lane==0) s_wwsum = s;
    }
    __syncthreads();

    // ---- Phase F: memory write + link update (old prec)
    #pragma unroll
    for (int e=0;e<16;e++){
      int f = tid + 512*e;
      int m = f >> 7, w = f & 127;
      mem[m*MEMLD+w] = mem[m*MEMLD+w]*(1.0f - ww[m]*er[w]) + ww[m]*wv[w];
    }
    #pragma unroll
    for (int e=0;e<8;e++){
      int f = tid + 512*e;
      int i = f >> 6, j = f & 63;
      float lv = (1.0f - ww[i] - ww[j])*link[i*LNKLD+j] + ww[i]*prec[j];
      link[i*LNKLD+j] = (i==j) ? 0.0f : lv;
    }
    __syncthreads();

    // ---- Phase G: precedence update + post-write mem norms
    if (tid < M) prec[tid] = (1.0f - s_wwsum)*prec[tid] + ww[tid];
    {
      int row = tid >> 3, sub = tid & 7;
      float ss = 0.f;
      #pragma unroll
      for (int i=0;i<16;i++){ float v = mem[row*MEMLD + sub + 8*i]; ss += v*v; }
      ss += __shfl_down(ss,4,8); ss += __shfl_down(ss,2,8); ss += __shfl_down(ss,1,8);
      if (sub==0) memnorm[row] = 1.0f/(sqrtf(ss)+DELTA);
    }
    __syncthreads();

    // ---- Phase H: read content scores (post-write memory)
    {
      int r = tid >> 7, m = (tid >> 1) & 63, sub = tid & 1;
      float d = 0.f;
      #pragma unroll 8
      for (int i=0;i<64;i++){ int e = sub + 2*i; d += mem[m*MEMLD + e]*rk[r*W + e]; }
      d += __shfl_down(d,1,2);
      if (sub==0) cwm[r*M+m] = d * memnorm[m] * s_rkinv[r] * rstr[r];
    }
    __syncthreads();

    // ---- Phase I: per-head softmax over M
    if (wave < RH){
      int r = wave;
      float x = cwm[r*M + lane];
      float mx = waveAllMax(x);
      float e = expf(x-mx);
      float s = waveAllSum(e);
      cwm[r*M+lane] = e/s;
    }
    __syncthreads();

    // ---- Phase J: fwd/bwd via link (old rw)
    if (tid < 256){
      int r = tid >> 6, i = tid & 63;
      float a = 0.f;
      #pragma unroll 8
      for (int j=0;j<M;j++) a += link[i*LNKLD+j]*rw[r*M+j];
      fwd[r*M+i] = a;
    } else {
      int q = tid - 256;
      int r = q >> 6, j = q & 63;
      float a = 0.f;
      #pragma unroll 8
      for (int i=0;i<M;i++) a += rw[r*M+i]*link[i*LNKLD+j];
      bwd[r*M+j] = a;
    }
    __syncthreads();

    // ---- Phase K: read weights update
    if (tid < RH*M){
      int r = tid >> 6;
      rw[tid] = rmode[3*r]*bwd[tid] + rmode[3*r+1]*fwd[tid] + rmode[3*r+2]*cwm[tid];
    }
    __syncthreads();

    // ---- Phase L: read vectors -> stash (no trailing barrier; next phase
    //       only writes gates[], disjoint from mem/rw reads here)
    {
      int r = tid >> 7, w = tid & 127;
      float a = 0.f;
      #pragma unroll 8
      for (int m=0;m<M;m++) a += rw[r*M+m]*mem[m*MEMLD+w];
      stash[bt*640 + 128 + tid] = a;
    }
  }
}

extern "C" void kernel_launch(void* const* d_in, const int* in_sizes, int n_in,
                              void* d_out, int out_size, void* d_ws, size_t ws_size,
                              hipStream_t stream)
{
  const int*   tokens  = (const int*)d_in[0];
  const float* emb     = (const float*)d_in[1];
  const float* w_ih0   = (const float*)d_in[2];
  const float* w_hh0   = (const float*)d_in[3];
  const float* b_ih0   = (const float*)d_in[4];
  const float* b_hh0   = (const float*)d_in[5];
  const float* w_ih1   = (const float*)d_in[6];
  const float* w_hh1   = (const float*)d_in[7];
  const float* b_ih1   = (const float*)d_in[8];
  const float* b_hh1   = (const float*)d_in[9];
  const float* w_iface = (const float*)d_in[10];
  const float* b_iface = (const float*)d_in[11];
  const float* w_out   = (const float*)d_in[12];
  const float* b_out   = (const float*)d_in[13];
  const float* w_fc    = (const float*)d_in[14];
  const float* b_fc    = (const float*)d_in[15];
  const float* h0      = (const float*)d_in[16];
  float* out = (float*)d_out;
  float* ws  = (float*)d_ws;

  float* xw0     = ws;                   // 512*512    = 262144
  float* whh0T   = xw0     + 262144;     // 128*512    = 65536
  float* w1catT  = whh0T   + 65536;      // 256*512    = 131072
  float* wifaceT = w1catT  + 131072;     // 128*919    = 117632
  float* wih0T   = wifaceT + 117632;     // 128*512    = 65536 (temp for xw0)
  float* stash   = wih0T   + 65536;      // 16384*640  = 10485760
  // total ~11.1M floats = 44.5 MB

  auto tp = [&](const float* in, float* o, int rows, int cols, int use){
    int total = rows*use;
    k_transpose<<<(total+255)/256, 256, 0, stream>>>(in, o, rows, cols, use);
  };
  tp(w_ih0,   wih0T,          512, 640, 128);
  tp(w_hh0,   whh0T,          512, 128, 128);
  tp(w_ih1,   w1catT,         512, 128, 128);
  tp(w_hh1,   w1catT+128*G4,  512, 128, 128);
  tp(w_iface, wifaceT,        919, 128, 128);
  k_xw0<<<VOCAB, 512, 0, stream>>>(emb, wih0T, b_ih0, b_hh0, xw0);
  k_dnc<<<B, 512, 0, stream>>>(tokens, xw0, whh0T, w1catT, b_ih1, b_hh1,
                               wifaceT, b_iface, h0, stash);
  k_tail<<<(B*T)/32, 512, 0, stream>>>(stash, w_out, b_out, w_fc, b_fc, out);
}